// Round 3
// baseline (13365.303 us; speedup 1.0000x reference)
//
#include <hip/hip_runtime.h>

// GRU scan, 2 layers, B=64 T=4096 D=H=128 — layer-specialized waves.
// 4 persistent WGs x 16 batch rows x 512 threads (8 waves).
// Waves 0-3 compute layer 0, waves 4-7 compute layer 1 (skew 2 steps).
// Each wave owns 2 unit-groups (32 hidden units): 96 weight frags
// stationary in VGPR/AGPR.
//
// v4 = v1 (7030us two-barrier schedule, linear LDS layout) + accumulator
// DOUBLE-BUFFERING to break the gates->iMFMA WAR serialization:
//  * ar/az/an have A/B sets; step t gates read set(t&1), iMFMA(t+1) builds
//    the other set. Main loop unrolled x2 so set selection is compile-time.
//  * P2 interleaves per k-step s: {ds_read, 2 gate elems (old set),
//    6 iMFMA (new set)} — both pipes have independent work everywhere,
//    so MFMA and VALU overlap intra-wave and across the 2 waves/SIMD.
//  * First MFMA of each acc takes C=Z4 (no per-step zero-init movs;
//    bit-identical).
// Round-1 lesson: keep TWO barriers/step (merge regressed).
// Round-2 lesson: LDS bank conflicts are off the critical path (swizzle
// removed 11x conflicts, no speedup) — v1 linear layout restored.

#define Tlen 4096
#define Hd   128
#define Bsz  64

typedef __attribute__((ext_vector_type(8))) short short8;     // 8 bf16
typedef __attribute__((ext_vector_type(4))) short short4v;    // 4 bf16
typedef __attribute__((ext_vector_type(4))) float float4v;
typedef __attribute__((ext_vector_type(2))) unsigned int uint2v;

#define MFMA16(a, b, c) __builtin_amdgcn_mfma_f32_16x16x32_bf16((a), (b), (c), 0, 0, 0)

static __device__ __forceinline__ float fast_exp2(float x) {
#if __has_builtin(__builtin_amdgcn_exp2f)
  return __builtin_amdgcn_exp2f(x);
#else
  return exp2f(x);
#endif
}
static __device__ __forceinline__ float fast_rcp(float x) {
  return __builtin_amdgcn_rcpf(x);
}
static __device__ __forceinline__ short f2bf(float f) {  // RTNE fp32->bf16
  unsigned u = __builtin_bit_cast(unsigned, f);
  u = (u + 0x7FFFu + ((u >> 16) & 1u)) >> 16;
  return (short)u;
}
static __device__ __forceinline__ unsigned pk2bf(float a, float b) {  // lo=a hi=b
#if __has_builtin(__builtin_amdgcn_cvt_pk_bf16_f32)
  auto v = __builtin_amdgcn_cvt_pk_bf16_f32(a, b);
  return __builtin_bit_cast(unsigned, v);
#else
  return (unsigned)(unsigned short)f2bf(a) | ((unsigned)(unsigned short)f2bf(b) << 16);
#endif
}
static __device__ __forceinline__ short8 loadw8(const float* __restrict__ p) {
  short8 r;
  #pragma unroll
  for (int j = 0; j < 8; ++j) r[j] = f2bf(p[j]);
  return r;
}

// LDS blocks (short indices). Block = 2048 shorts (16 rows x 128 k bf16).
// Frag-linear: addr(row, k) = (k>>5)*512 + ((k>>3)&3)*128 + row*8 + (k&7);
// reader lane l, kstep s does b128 at s*512 + l*8 (conflict-free).
#define XB   0
#define H0B  4096
#define H1B  8192
#define BLK  2048

// One gate element (G_, i_): consumes CR/CZ (r,z accs), CN (input n-part),
// ahv (hidden n-part), hp carry; writes hp + h into LDS.
#define GATE(CR, CZ, CN, G_, i_, wr_)                                       \
  {                                                                         \
    const float er = fast_exp2(fmaf(CR[G_][i_], nL, kr[G_]));               \
    const float rr = fast_rcp(1.0f + er);                                   \
    const float ez = fast_exp2(fmaf(CZ[G_][i_], nL, kz[G_]));               \
    const float zz = fast_rcp(1.0f + ez);                                   \
    float vv = fmaf(rr, fmaf(ahv[G_][i_], n2L, kh[G_]),                     \
                    fmaf(CN[G_][i_], n2L, ki[G_]));                         \
    vv = fminf(vv, 126.0f);                                                 \
    const float e2 = fast_exp2(vv);                                         \
    const float nn = (1.0f - e2) * fast_rcp(1.0f + e2);                     \
    const float hn = fmaf(zz, hp[G_][i_] - nn, nn);                         \
    hp[G_][i_] = hn;                                                        \
    Abuf[(wr_) + hw[G_] + (quad * 4 + i_) * 8] = f2bf(hn);                  \
  }

// One full step t_: P1 hMFMA into current set (CR,CZ)+ahv; barrier;
// P2 stage-x + interleaved {gates from current set | iMFMA into next set}.
#define STEP(t_, CR, CZ, CN, NR, NZ, NN)                                    \
  {                                                                         \
    const int par  = ((t_) & 1) * BLK;                                      \
    const int parx = BLK - par;                                             \
    const int tn = ((t_) + 2 < Tlen) ? ((t_) + 2) : (Tlen - 1);             \
    const float4v xv = *(const float4v*)(xg + (size_t)tn * Hd);             \
    const int hrd = hsel + parx;                                            \
    _Pragma("unroll")                                                       \
    for (int s = 0; s < 4; ++s) {                                           \
      const short8 a = *(const short8*)&Abuf[hrd + s * 512 + lane8];        \
      _Pragma("unroll")                                                     \
      for (int G = 0; G < 2; ++G) {                                         \
        CR[G] = MFMA16(a, fhr[G][s], CR[G]);                                \
        CZ[G] = MFMA16(a, fhz[G][s], CZ[G]);                                \
        ahv[G] = (s == 0) ? MFMA16(a, fhn[G][0], Z4)                        \
                          : MFMA16(a, fhn[G][s], ahv[G]);                   \
      }                                                                     \
    }                                                                       \
    __syncthreads();                                                        \
    {                                                                       \
      uint2v pp = {pk2bf(xv[0], xv[1]), pk2bf(xv[2], xv[3])};               \
      *(short4v*)&Abuf[XB + par + xwoff] = __builtin_bit_cast(short4v, pp); \
    }                                                                       \
    const bool gv = ((t_) >= glo) & ((t_) < ghi);                           \
    const int wr  = hsel + par;                                             \
    const int ird = isel + parx;                                            \
    _Pragma("unroll")                                                       \
    for (int s = 0; s < 4; ++s) {                                           \
      const short8 a = *(const short8*)&Abuf[ird + s * 512 + lane8];        \
      if (gv) {                                                             \
        _Pragma("unroll")                                                   \
        for (int ii = 0; ii < 2; ++ii) {                                    \
          GATE(CR, CZ, CN, (s >> 1), ((s & 1) * 2 + ii), wr);               \
        }                                                                   \
      }                                                                     \
      _Pragma("unroll")                                                     \
      for (int G = 0; G < 2; ++G) {                                         \
        if (s == 0) {                                                       \
          NR[G] = MFMA16(a, fxr[G][0], Z4);                                 \
          NZ[G] = MFMA16(a, fxz[G][0], Z4);                                 \
          NN[G] = MFMA16(a, fxn[G][0], Z4);                                 \
        } else {                                                            \
          NR[G] = MFMA16(a, fxr[G][s], NR[G]);                              \
          NZ[G] = MFMA16(a, fxz[G][s], NZ[G]);                              \
          NN[G] = MFMA16(a, fxn[G][s], NN[G]);                              \
        }                                                                   \
      }                                                                     \
    }                                                                       \
    __syncthreads();                                                        \
  }

__global__ __launch_bounds__(512, 2) void gru_scan(
    const float* __restrict__ x,
    const float* __restrict__ Wih0, const float* __restrict__ Whh0,
    const float* __restrict__ bih0, const float* __restrict__ bhh0,
    const float* __restrict__ Wih1, const float* __restrict__ Whh1,
    const float* __restrict__ bih1, const float* __restrict__ bhh1,
    float* __restrict__ out) {
  __shared__ alignas(16) short Abuf[12288];  // 24 KB

  const int tid   = threadIdx.x;
  const int wave  = tid >> 6;
  const int lane  = tid & 63;
  const int lc    = lane & 15;
  const int quad  = lane >> 4;
  const int q8    = quad * 8;
  const int lane8 = lane * 8;
  const int bbase = blockIdx.x * 16;

  const int wgrp = wave >> 2;     // 0 = layer0 waves, 1 = layer1 waves
  const int w4   = wave & 3;

  const float* Wi = wgrp ? Wih1 : Wih0;
  const float* Wh = wgrp ? Whh1 : Whh0;
  const float* bi = wgrp ? bih1 : bih0;
  const float* bh = wgrp ? bhh1 : bhh0;

  // ---- stationary weight fragments: ONE layer, 2 unit-groups -------------
  short8 fxr[2][4], fxz[2][4], fxn[2][4];   // input-side (Wih)
  short8 fhr[2][4], fhz[2][4], fhn[2][4];   // hidden-side (Whh)
  float kr[2], kz[2], ki[2], kh[2];
  const float nL  = -1.44269504088896f;     // -log2(e)
  const float n2L = -2.88539008177793f;     // -2*log2(e)
  #pragma unroll
  for (int G = 0; G < 2; ++G) {
    const int c = 32 * w4 + 16 * G + lc;    // unit (column) this lane owns
    #pragma unroll
    for (int s = 0; s < 4; ++s) {
      const int k = 32 * s + q8;
      fxr[G][s] = loadw8(Wi + (c)       * Hd + k);
      fxz[G][s] = loadw8(Wi + (128 + c) * Hd + k);
      fxn[G][s] = loadw8(Wi + (256 + c) * Hd + k);
      fhr[G][s] = loadw8(Wh + (c)       * Hd + k);
      fhz[G][s] = loadw8(Wh + (128 + c) * Hd + k);
      fhn[G][s] = loadw8(Wh + (256 + c) * Hd + k);
    }
    kr[G] = nL  * (bi[c] + bh[c]);
    kz[G] = nL  * (bi[128 + c] + bh[128 + c]);
    ki[G] = n2L * bi[256 + c];
    kh[G] = n2L * bh[256 + c];
  }

  // LDS bases per wave-group
  const int hsel = wgrp ? H1B : H0B;   // h-part read (P1) + h write (P2)
  const int isel = wgrp ? H0B : XB;    // input-part read (P2)

  // h-write offsets (frag layout, k = unit): u>>5 == w4 for our groups
  int hw[2];
  #pragma unroll
  for (int G = 0; G < 2; ++G)
    hw[G] = w4 * 512 + (2 * G + (lc >> 3)) * 128 + (lc & 7);

  // x staging slots: thread -> (row, k0..k0+3)
  const int xrow = tid >> 5;
  const int xk0  = 4 * (tid & 31);
  const int xwoff = (xk0 >> 5) * 512 + ((xk0 >> 3) & 3) * 128 + xrow * 8 + (xk0 & 7);
  const float* xg = x + (size_t)(bbase + xrow) * (Tlen * Hd) + xk0;

  // gate-validity window: L0 steps t in [0,T), L1 sigma=t-2 -> t in [2,T+2)
  const int glo = wgrp ? 2 : 0;
  const int ghi = glo + Tlen;

  // ---- prologue ----------------------------------------------------------
  {
    int* zb = (int*)Abuf;               // zero H0/H1 blocks: dwords [2048,6144)
    #pragma unroll
    for (int i = 0; i < 8; ++i) zb[2048 + tid + 512 * i] = 0;
    const float4v v0 = *(const float4v*)(xg);                 // x(0)
    const float4v v1 = *(const float4v*)(xg + Hd);            // x(1)
    uint2v p0 = {pk2bf(v0[0], v0[1]), pk2bf(v0[2], v0[3])};
    uint2v p1 = {pk2bf(v1[0], v1[1]), pk2bf(v1[2], v1[3])};
    *(short4v*)&Abuf[XB + xwoff]       = __builtin_bit_cast(short4v, p0);
    *(short4v*)&Abuf[XB + BLK + xwoff] = __builtin_bit_cast(short4v, p1);
  }
  __syncthreads();

  const float4v Z4 = {0.f, 0.f, 0.f, 0.f};
  // acc sets: A used by even steps, B by odd steps. ahv/hp not double-buffered
  // (P1(t+1) strictly follows gates(t); hp is a carry).
  float4v arA[2], azA[2], anA[2];
  float4v arB[2], azB[2], anB[2];
  float4v ahv[2], hp[2] = {Z4, Z4};

  // prologue "P2(-1)": input-part MFMAs into set A
  // (L0: x(0) from X[0]; L1: zeros from H0[0])
  #pragma unroll
  for (int s = 0; s < 4; ++s) {
    const short8 a = *(const short8*)&Abuf[isel + s * 512 + lane8];
    #pragma unroll
    for (int G = 0; G < 2; ++G) {
      if (s == 0) {
        arA[G] = MFMA16(a, fxr[G][0], Z4);
        azA[G] = MFMA16(a, fxz[G][0], Z4);
        anA[G] = MFMA16(a, fxn[G][0], Z4);
      } else {
        arA[G] = MFMA16(a, fxr[G][s], arA[G]);
        azA[G] = MFMA16(a, fxz[G][s], azA[G]);
        anA[G] = MFMA16(a, fxn[G][s], anA[G]);
      }
    }
  }

  // ---- main loop: T+2 iterations, unrolled x2 (4098 = 2*2049) ------------
  for (int tt = 0; tt < Tlen + 2; tt += 2) {
    STEP(tt,     arA, azA, anA, arB, azB, anB);
    STEP(tt + 1, arB, azB, anB, arA, azA, anA);
  }

  // ---- output: L0 waves hold h0(T-1), L1 waves hold h1(T-1) --------------
  #pragma unroll
  for (int G = 0; G < 2; ++G) {
    const int u = 32 * w4 + 16 * G + lc;
    #pragma unroll
    for (int i = 0; i < 4; ++i) {
      const int b = bbase + quad * 4 + i;
      out[wgrp * (Bsz * Hd) + b * Hd + u] = hp[G][i];
    }
  }
}

extern "C" void kernel_launch(void* const* d_in, const int* in_sizes, int n_in,
                              void* d_out, int out_size, void* d_ws, size_t ws_size,
                              hipStream_t stream) {
  (void)in_sizes; (void)n_in; (void)out_size; (void)d_ws; (void)ws_size;
  gru_scan<<<4, 512, 0, stream>>>(
      (const float*)d_in[0],
      (const float*)d_in[1], (const float*)d_in[2],
      (const float*)d_in[3], (const float*)d_in[4],
      (const float*)d_in[5], (const float*)d_in[6],
      (const float*)d_in[7], (const float*)d_in[8],
      (float*)d_out);
}